// Round 5
// baseline (90.627 us; speedup 1.0000x reference)
//
#include <hip/hip_runtime.h>
#include <hip/hip_bf16.h>

// out = x @ W^T + bias (memristor constants cancel exactly; see round-0).
// M=512, N=2048, K=2048 fp32 -> bf16 MFMA, fp32 accum.
//
// Round-5: two-phase.
//  Phase 1: convert x,W fp32 -> bf16 into d_ws (10.5 MB).
//  Phase 2: GEMM staged via __builtin_amdgcn_global_load_lds (16B/lane DMA,
//   no cvt / no ds_write / no VGPR round-trip in the hot loop). DMA forbids
//   LDS padding, so bank conflicts are killed with an XOR column swizzle:
//   LDS[row][chunk] holds global chunk (chunk ^ (row&7)); fragment readers
//   apply the same XOR -> ds_read_b128 spreads all 32 banks, 2-way (free).
// 512 thr = 8 waves = 2x2 spatial x 2-way K-split, BK=128, dbuf LDS.

typedef float  float4_t __attribute__((ext_vector_type(4)));
typedef short  short8_t __attribute__((ext_vector_type(8)));
typedef float  floatx4  __attribute__((ext_vector_type(4)));

constexpr int M = 512, N = 2048, K = 2048;
constexpr int BM = 64, BN = 64, BK = 128;
constexpr int NT = K / BK;            // 16 k-tiles

// ---------------- phase 1: fp32 -> bf16 into d_ws ----------------
constexpr int NX = M * K;             // 1,048,576 (2 MB bf16)
constexpr int NW = N * K;             // 4,194,304 (8 MB bf16)
constexpr int NCONV4 = (NX + NW) / 4; // 1,310,720 float4s; NX/4 = 262144 (block-aligned)

__global__ __launch_bounds__(256)
void convert_bf16(const float* __restrict__ x, const float* __restrict__ w,
                  unsigned long long* __restrict__ xb,
                  unsigned long long* __restrict__ wb)
{
    const int i = blockIdx.x * 256 + threadIdx.x;        // one float4 per thread
    const bool isx = i < NX / 4;
    const float4_t v = isx ? *(const float4_t*)(x + 4 * (size_t)i)
                           : *(const float4_t*)(w + 4 * (size_t)(i - NX / 4));
    union { __hip_bfloat16 h[4]; unsigned long long u; } p;
    p.h[0] = __float2bfloat16(v.x);
    p.h[1] = __float2bfloat16(v.y);
    p.h[2] = __float2bfloat16(v.z);
    p.h[3] = __float2bfloat16(v.w);
    if (isx) xb[i] = p.u; else wb[i - NX / 4] = p.u;
}

// ---------------- phase 2: bf16 MFMA GEMM with DMA staging ----------------
__device__ __forceinline__ void dma16(const void* g, void* l) {
    __builtin_amdgcn_global_load_lds(
        (const __attribute__((address_space(1))) unsigned int*)g,
        (__attribute__((address_space(3))) unsigned int*)l, 16, 0, 0);
}

__global__ __launch_bounds__(512)
void memristor_gemm(const __hip_bfloat16* __restrict__ xb,
                    const __hip_bfloat16* __restrict__ wb,
                    const float* __restrict__ bias, float* __restrict__ out)
{
    // unpadded (DMA requirement): row = 128 bf16 = 256 B
    __shared__ __align__(16) __hip_bfloat16 As[2][BM][BK];   // 2 x 16 KB
    __shared__ __align__(16) __hip_bfloat16 Bs[2][BN][BK];   // 2 x 16 KB

    const int tid  = threadIdx.x;
    const int bn   = blockIdx.x, bm = blockIdx.y;
    const int lane = tid & 63;
    const int wave = tid >> 6;        // 0..7
    const int wsp  = wave & 3;        // 2x2 spatial quadrant
    const int kp   = wave >> 2;       // k-half
    const int wm   = (wsp >> 1) * 32;
    const int wn   = (wsp & 1) * 32;
    const int l16  = lane & 15;
    const int quad = lane >> 4;
    const int key  = l16 & 7;         // XOR swizzle key (= row mod 8 for frag rows)

    // DMA staging map: wave w stages A rows 8w..8w+7 and B rows 8w..8w+7,
    // as 2 chunks of 4 rows (1 KB) each. Within a chunk: lane -> row l>>4,
    // 16B-col (l&15). Source column is XOR-swizzled by (row mod 8).
    const int r_in = lane >> 4;       // 0..3
    const int cp   = lane & 15;       // physical 16B chunk in row

    floatx4 acc[2][2];
    #pragma unroll
    for (int i = 0; i < 2; ++i)
        #pragma unroll
        for (int j = 0; j < 2; ++j)
            acc[i][j] = (floatx4){0.f, 0.f, 0.f, 0.f};

    auto stage_dma = [&](int buf, int k0) {
        #pragma unroll
        for (int d = 0; d < 2; ++d) {
            const int rl = wave * 8 + d * 4 + r_in;          // local row 0..63
            const int cl = cp ^ (rl & 7);                    // logical 16B chunk
            dma16(xb + ((size_t)(bm * BM + rl) * K + k0 + cl * 8),
                  &As[buf][wave * 8 + d * 4][0]);
            dma16(wb + ((size_t)(bn * BN + rl) * K + k0 + cl * 8),
                  &Bs[buf][wave * 8 + d * 4][0]);
        }
    };

    auto compute = [&](int buf) {
        #pragma unroll
        for (int s = 0; s < 2; ++s) {
            const int ch = (kp * 8 + s * 4 + quad) ^ key;    // swizzled 16B chunk
            short8_t af0 = *(const short8_t*)&As[buf][wm + l16][ch * 8];
            short8_t af1 = *(const short8_t*)&As[buf][wm + 16 + l16][ch * 8];
            short8_t bf0 = *(const short8_t*)&Bs[buf][wn + l16][ch * 8];
            short8_t bf1 = *(const short8_t*)&Bs[buf][wn + 16 + l16][ch * 8];
            acc[0][0] = __builtin_amdgcn_mfma_f32_16x16x32_bf16(af0, bf0, acc[0][0], 0, 0, 0);
            acc[0][1] = __builtin_amdgcn_mfma_f32_16x16x32_bf16(af0, bf1, acc[0][1], 0, 0, 0);
            acc[1][0] = __builtin_amdgcn_mfma_f32_16x16x32_bf16(af1, bf0, acc[1][0], 0, 0, 0);
            acc[1][1] = __builtin_amdgcn_mfma_f32_16x16x32_bf16(af1, bf1, acc[1][1], 0, 0, 0);
        }
    };

    stage_dma(0, 0);
    __syncthreads();                  // drains the DMA (vmcnt 0)

    for (int t = 0; t < NT; ++t) {
        const int cur = t & 1;
        if (t + 1 < NT) stage_dma(cur ^ 1, (t + 1) * BK);   // in flight over compute
        compute(cur);
        __syncthreads();              // drains next tile's DMA + ds reads
    }

    // epilogue: 2-way K-split reduction through LDS (As reused; 18432 B < 32 KB)
    float* scrb = (float*)&As[0][0][0];
    if (kp == 1) {
        #pragma unroll
        for (int i = 0; i < 2; ++i)
            #pragma unroll
            for (int j = 0; j < 2; ++j) {
                float* p = scrb + ((wsp * 32 + j * 16 + l16) * 36 + i * 16 + quad * 4);
                *(floatx4*)p = acc[i][j];
            }
    }
    __syncthreads();
    if (kp == 0) {
        #pragma unroll
        for (int j = 0; j < 2; ++j) {
            const int col = bn * BN + wn + j * 16 + l16;
            const float bv = bias[col];
            #pragma unroll
            for (int i = 0; i < 2; ++i) {
                const floatx4 part = *(const floatx4*)(
                    scrb + ((wsp * 32 + j * 16 + l16) * 36 + i * 16 + quad * 4));
                const int row0 = bm * BM + wm + i * 16 + quad * 4;
                #pragma unroll
                for (int r = 0; r < 4; ++r)
                    out[(size_t)(row0 + r) * N + col] = acc[i][j][r] + part[r] + bv;
            }
        }
    }
}

extern "C" void kernel_launch(void* const* d_in, const int* in_sizes, int n_in,
                              void* d_out, int out_size, void* d_ws, size_t ws_size,
                              hipStream_t stream) {
    const float* x    = (const float*)d_in[0];   // (512, 2048)
    const float* w    = (const float*)d_in[1];   // (2048, 2048) = (N, K)
    const float* bias = (const float*)d_in[2];   // (2048,)
    float* out = (float*)d_out;                  // (512, 2048)

    unsigned long long* xb = (unsigned long long*)d_ws;            // 2 MB bf16 x
    unsigned long long* wb = xb + NX / 4;                          // 8 MB bf16 W

    convert_bf16<<<NCONV4 / 256, 256, 0, stream>>>(x, w, xb, wb);

    dim3 grid(N / BN, M / BM);                   // (32, 8) = 256 blocks, 1/CU
    memristor_gemm<<<grid, 512, 0, stream>>>(
        (const __hip_bfloat16*)xb, (const __hip_bfloat16*)wb, bias, out);
}

// Round 6
// 88.266 us; speedup vs baseline: 1.0267x; 1.0267x over previous
//
#include <hip/hip_runtime.h>
#include <hip/hip_bf16.h>

// out = x @ W^T + bias (memristor constants cancel exactly; see round-0).
// M=512, N=2048, K=2048 fp32 -> bf16 MFMA, fp32 accum.
//
// Round-6: break the latency plateau. R2/R4/R5 all ~29us with 1 block/CU --
// staging-path-invariant => latency/occupancy-bound, not staging-bound.
// Now split-K=4 across blockIdx.z: 1024 blocks = 4 blocks/CU = 32 waves/CU,
// so co-resident blocks cover each other's barrier drains (m114 overlap).
//  Phase 1: convert x,W fp32 -> bf16 into d_ws.
//  Phase 2: DMA-staged GEMM (global_load_lds 16B, XOR-swizzled LDS),
//           each z-slice does K/4=512, writes fp32 partial to d_ws.
//  Phase 3: reduce 4 partials + bias -> out.

typedef float  float4_t __attribute__((ext_vector_type(4)));
typedef short  short8_t __attribute__((ext_vector_type(8)));
typedef float  floatx4  __attribute__((ext_vector_type(4)));

constexpr int M = 512, N = 2048, K = 2048;
constexpr int BM = 64, BN = 64, BK = 128;
constexpr int KSPLIT = 4;
constexpr int KS  = K / KSPLIT;       // 512 per z-slice
constexpr int NTL = KS / BK;          // 4 k-tiles per slice

// ---------------- phase 1: fp32 -> bf16 into d_ws ----------------
constexpr int NX = M * K;             // 1,048,576 (2 MB bf16)
constexpr int NW = N * K;             // 4,194,304 (8 MB bf16)
constexpr int NCONV4 = (NX + NW) / 4; // float4 count; NX/4 block-aligned

__global__ __launch_bounds__(256)
void convert_bf16(const float* __restrict__ x, const float* __restrict__ w,
                  unsigned long long* __restrict__ xb,
                  unsigned long long* __restrict__ wb)
{
    const int i = blockIdx.x * 256 + threadIdx.x;
    const bool isx = i < NX / 4;
    const float4_t v = isx ? *(const float4_t*)(x + 4 * (size_t)i)
                           : *(const float4_t*)(w + 4 * (size_t)(i - NX / 4));
    union { __hip_bfloat16 h[4]; unsigned long long u; } p;
    p.h[0] = __float2bfloat16(v.x);
    p.h[1] = __float2bfloat16(v.y);
    p.h[2] = __float2bfloat16(v.z);
    p.h[3] = __float2bfloat16(v.w);
    if (isx) xb[i] = p.u; else wb[i - NX / 4] = p.u;
}

// ---------------- phase 2: DMA-staged bf16 GEMM, split-K partials ----------
__device__ __forceinline__ void dma16(const void* g, void* l) {
    __builtin_amdgcn_global_load_lds(
        (const __attribute__((address_space(1))) unsigned int*)g,
        (__attribute__((address_space(3))) unsigned int*)l, 16, 0, 0);
}

__global__ __launch_bounds__(512)
void memristor_gemm(const __hip_bfloat16* __restrict__ xb,
                    const __hip_bfloat16* __restrict__ wb,
                    float* __restrict__ part)
{
    __shared__ __align__(16) __hip_bfloat16 As[2][BM][BK];   // 2 x 16 KB
    __shared__ __align__(16) __hip_bfloat16 Bs[2][BN][BK];

    const int tid  = threadIdx.x;
    const int bn   = blockIdx.x, bm = blockIdx.y, bz = blockIdx.z;
    const int lane = tid & 63;
    const int wave = tid >> 6;        // 0..7
    const int wsp  = wave & 3;        // 2x2 spatial quadrant
    const int kp   = wave >> 2;       // k-half within BK
    const int wm   = (wsp >> 1) * 32;
    const int wn   = (wsp & 1) * 32;
    const int l16  = lane & 15;
    const int quad = lane >> 4;
    const int key  = l16 & 7;         // XOR swizzle key

    const int r_in = lane >> 4;       // row within 4-row DMA chunk
    const int cp   = lane & 15;       // physical 16B chunk in row

    floatx4 acc[2][2];
    #pragma unroll
    for (int i = 0; i < 2; ++i)
        #pragma unroll
        for (int j = 0; j < 2; ++j)
            acc[i][j] = (floatx4){0.f, 0.f, 0.f, 0.f};

    const int kbase = bz * KS;

    auto stage_dma = [&](int buf, int k0) {
        #pragma unroll
        for (int d = 0; d < 2; ++d) {
            const int rl = wave * 8 + d * 4 + r_in;          // local row 0..63
            const int cl = cp ^ (rl & 7);                    // swizzled 16B chunk
            dma16(xb + ((size_t)(bm * BM + rl) * K + k0 + cl * 8),
                  &As[buf][wave * 8 + d * 4][0]);
            dma16(wb + ((size_t)(bn * BN + rl) * K + k0 + cl * 8),
                  &Bs[buf][wave * 8 + d * 4][0]);
        }
    };

    auto compute = [&](int buf) {
        #pragma unroll
        for (int s = 0; s < 2; ++s) {
            const int ch = (kp * 8 + s * 4 + quad) ^ key;    // swizzled chunk
            short8_t af0 = *(const short8_t*)&As[buf][wm + l16][ch * 8];
            short8_t af1 = *(const short8_t*)&As[buf][wm + 16 + l16][ch * 8];
            short8_t bf0 = *(const short8_t*)&Bs[buf][wn + l16][ch * 8];
            short8_t bf1 = *(const short8_t*)&Bs[buf][wn + 16 + l16][ch * 8];
            acc[0][0] = __builtin_amdgcn_mfma_f32_16x16x32_bf16(af0, bf0, acc[0][0], 0, 0, 0);
            acc[0][1] = __builtin_amdgcn_mfma_f32_16x16x32_bf16(af0, bf1, acc[0][1], 0, 0, 0);
            acc[1][0] = __builtin_amdgcn_mfma_f32_16x16x32_bf16(af1, bf0, acc[1][0], 0, 0, 0);
            acc[1][1] = __builtin_amdgcn_mfma_f32_16x16x32_bf16(af1, bf1, acc[1][1], 0, 0, 0);
        }
    };

    stage_dma(0, kbase);
    __syncthreads();

    #pragma unroll
    for (int t = 0; t < NTL; ++t) {
        const int cur = t & 1;
        if (t + 1 < NTL) stage_dma(cur ^ 1, kbase + (t + 1) * BK);
        compute(cur);
        __syncthreads();
    }

    // in-block 2-way kp reduction through LDS, then write fp32 partial
    float* scrb = (float*)&As[0][0][0];
    if (kp == 1) {
        #pragma unroll
        for (int i = 0; i < 2; ++i)
            #pragma unroll
            for (int j = 0; j < 2; ++j) {
                float* p = scrb + ((wsp * 32 + j * 16 + l16) * 36 + i * 16 + quad * 4);
                *(floatx4*)p = acc[i][j];
            }
    }
    __syncthreads();
    if (kp == 0) {
        float* pslice = part + (size_t)bz * M * N;
        #pragma unroll
        for (int j = 0; j < 2; ++j) {
            const int col = bn * BN + wn + j * 16 + l16;
            #pragma unroll
            for (int i = 0; i < 2; ++i) {
                const floatx4 po = *(const floatx4*)(
                    scrb + ((wsp * 32 + j * 16 + l16) * 36 + i * 16 + quad * 4));
                const int row0 = bm * BM + wm + i * 16 + quad * 4;
                #pragma unroll
                for (int r = 0; r < 4; ++r)
                    pslice[(size_t)(row0 + r) * N + col] = acc[i][j][r] + po[r];
            }
        }
    }
}

// ---------------- phase 3: sum partials + bias -> out ----------------
__global__ __launch_bounds__(256)
void reduce_bias(const float* __restrict__ part, const float* __restrict__ bias,
                 float* __restrict__ out)
{
    const size_t off = 4 * ((size_t)blockIdx.x * 256 + threadIdx.x);
    constexpr size_t MN = (size_t)M * N;
    float4_t s = *(const float4_t*)(part + off);
    s += *(const float4_t*)(part + MN + off);
    s += *(const float4_t*)(part + 2 * MN + off);
    s += *(const float4_t*)(part + 3 * MN + off);
    s += *(const float4_t*)(bias + (off & (N - 1)));
    *(float4_t*)(out + off) = s;
}

extern "C" void kernel_launch(void* const* d_in, const int* in_sizes, int n_in,
                              void* d_out, int out_size, void* d_ws, size_t ws_size,
                              hipStream_t stream) {
    const float* x    = (const float*)d_in[0];   // (512, 2048)
    const float* w    = (const float*)d_in[1];   // (2048, 2048) = (N, K)
    const float* bias = (const float*)d_in[2];   // (2048,)
    float* out = (float*)d_out;                  // (512, 2048)

    unsigned long long* xb = (unsigned long long*)d_ws;          // 2 MB bf16 x
    unsigned long long* wb = xb + NX / 4;                        // 8 MB bf16 W
    float* part = (float*)((char*)d_ws + (size_t)(NX + NW) * 2); // 16 MB partials

    convert_bf16<<<NCONV4 / 256, 256, 0, stream>>>(x, w, xb, wb);

    dim3 grid(N / BN, M / BM, KSPLIT);           // (32, 8, 4) = 1024 blocks
    memristor_gemm<<<grid, 512, 0, stream>>>(
        (const __hip_bfloat16*)xb, (const __hip_bfloat16*)wb, part);

    reduce_bias<<<(M * N / 4) / 256, 256, 0, stream>>>(part, bias, out);
}

// Round 7
// 85.609 us; speedup vs baseline: 1.0586x; 1.0310x over previous
//
#include <hip/hip_runtime.h>
#include <hip/hip_bf16.h>

// out = x @ W^T + bias (memristor constants cancel exactly; see round-0).
// M=512, N=2048, K=2048 fp32 -> bf16 MFMA, fp32 accum.
//
// Round-7: R6's LDS footprint was 64 KB/block (BK=128 dbuf) -> only 2
// blocks/CU = 16 waves. Occupancy scaling so far: 4 waves=43us, 8=29us,
// 16=~24us (latency-bound). Now BK=64 dbuf = 32 KB/block -> 4 blocks/CU =
// 32 waves/CU (HW max), __launch_bounds__(512,8) to pin VGPR<=64.
//  Phase 1: convert x,W fp32 -> bf16 into d_ws.
//  Phase 2: split-K=4 DMA-staged GEMM (global_load_lds 16B, XOR swizzle).
//  Phase 3: reduce 4 partials + bias -> out.

typedef float  float4_t __attribute__((ext_vector_type(4)));
typedef short  short8_t __attribute__((ext_vector_type(8)));
typedef float  floatx4  __attribute__((ext_vector_type(4)));

constexpr int M = 512, N = 2048, K = 2048;
constexpr int BM = 64, BN = 64, BK = 64;
constexpr int KSPLIT = 4;
constexpr int KS  = K / KSPLIT;       // 512 per z-slice
constexpr int NTL = KS / BK;          // 8 k-tiles per slice

// ---------------- phase 1: fp32 -> bf16 into d_ws ----------------
constexpr int NX = M * K;             // 1,048,576 (2 MB bf16)
constexpr int NW = N * K;             // 4,194,304 (8 MB bf16)
constexpr int NCONV4 = (NX + NW) / 4;

__global__ __launch_bounds__(256)
void convert_bf16(const float* __restrict__ x, const float* __restrict__ w,
                  unsigned long long* __restrict__ xb,
                  unsigned long long* __restrict__ wb)
{
    const int i = blockIdx.x * 256 + threadIdx.x;
    const bool isx = i < NX / 4;
    const float4_t v = isx ? *(const float4_t*)(x + 4 * (size_t)i)
                           : *(const float4_t*)(w + 4 * (size_t)(i - NX / 4));
    union { __hip_bfloat16 h[4]; unsigned long long u; } p;
    p.h[0] = __float2bfloat16(v.x);
    p.h[1] = __float2bfloat16(v.y);
    p.h[2] = __float2bfloat16(v.z);
    p.h[3] = __float2bfloat16(v.w);
    if (isx) xb[i] = p.u; else wb[i - NX / 4] = p.u;
}

// ---------------- phase 2: DMA-staged bf16 GEMM, split-K partials ----------
__device__ __forceinline__ void dma16(const void* g, void* l) {
    __builtin_amdgcn_global_load_lds(
        (const __attribute__((address_space(1))) unsigned int*)g,
        (__attribute__((address_space(3))) unsigned int*)l, 16, 0, 0);
}

typedef __hip_bfloat16 tile_t[BM][BK];   // 8 KB per buffer

__global__ __launch_bounds__(512, 8)     // 8 waves/EU -> VGPR<=64, 4 blk/CU
void memristor_gemm(const __hip_bfloat16* __restrict__ xb,
                    const __hip_bfloat16* __restrict__ wb,
                    float* __restrict__ part)
{
    __shared__ __align__(16) unsigned char smem[32768];   // 4 blocks/CU by LDS
    tile_t* Asb = (tile_t*)smem;              // Asb[2]: 16 KB
    tile_t* Bsb = (tile_t*)(smem + 16384);    // Bsb[2]: 16 KB

    const int tid  = threadIdx.x;
    const int bn   = blockIdx.x, bm = blockIdx.y, bz = blockIdx.z;
    const int lane = tid & 63;
    const int wave = tid >> 6;        // 0..7
    const int wsp  = wave & 3;        // 2x2 spatial quadrant
    const int kp   = wave >> 2;       // k-half within BK (32 elems each)
    const int wm   = (wsp >> 1) * 32;
    const int wn   = (wsp & 1) * 32;
    const int l16  = lane & 15;
    const int quad = lane >> 4;
    const int key  = l16 & 7;         // XOR swizzle key (= row&7 for frag rows)

    // DMA map: wave w stages A rows [8w,8w+8) and B rows [8w,8w+8) as one
    // 1 KB DMA each. lane -> (row = 8w + lane>>3, 16B-chunk = lane&7),
    // source chunk XOR-swizzled by row&7 (== lane>>3 here).
    const int dr = lane >> 3;         // row within the 8-row DMA group
    const int dc = (lane & 7) ^ dr;   // swizzled source 16B chunk (0..7)

    floatx4 acc[2][2];
    #pragma unroll
    for (int i = 0; i < 2; ++i)
        #pragma unroll
        for (int j = 0; j < 2; ++j)
            acc[i][j] = (floatx4){0.f, 0.f, 0.f, 0.f};

    const int kbase = bz * KS;

    auto stage_dma = [&](int buf, int k0) {
        const int rl = wave * 8 + dr;
        dma16(xb + ((size_t)(bm * BM + rl) * K + k0 + dc * 8),
              &Asb[buf][wave * 8][0]);
        dma16(wb + ((size_t)(bn * BN + rl) * K + k0 + dc * 8),
              &Bsb[buf][wave * 8][0]);
    };

    auto compute = [&](int buf) {
        const int ch = (kp * 4 + quad) ^ key;   // physical 16B chunk 0..7
        short8_t af0 = *(const short8_t*)&Asb[buf][wm + l16][ch * 8];
        short8_t af1 = *(const short8_t*)&Asb[buf][wm + 16 + l16][ch * 8];
        short8_t bf0 = *(const short8_t*)&Bsb[buf][wn + l16][ch * 8];
        short8_t bf1 = *(const short8_t*)&Bsb[buf][wn + 16 + l16][ch * 8];
        acc[0][0] = __builtin_amdgcn_mfma_f32_16x16x32_bf16(af0, bf0, acc[0][0], 0, 0, 0);
        acc[0][1] = __builtin_amdgcn_mfma_f32_16x16x32_bf16(af0, bf1, acc[0][1], 0, 0, 0);
        acc[1][0] = __builtin_amdgcn_mfma_f32_16x16x32_bf16(af1, bf0, acc[1][0], 0, 0, 0);
        acc[1][1] = __builtin_amdgcn_mfma_f32_16x16x32_bf16(af1, bf1, acc[1][1], 0, 0, 0);
    };

    stage_dma(0, kbase);
    __syncthreads();

    #pragma unroll
    for (int t = 0; t < NTL; ++t) {
        const int cur = t & 1;
        if (t + 1 < NTL) stage_dma(cur ^ 1, kbase + (t + 1) * BK);
        compute(cur);
        __syncthreads();
    }

    // in-block 2-way kp reduction through LDS (scratch aliases whole smem)
    float* scrb = (float*)smem;       // 18432 B <= 32768 B
    if (kp == 1) {
        #pragma unroll
        for (int i = 0; i < 2; ++i)
            #pragma unroll
            for (int j = 0; j < 2; ++j) {
                float* p = scrb + ((wsp * 32 + j * 16 + l16) * 36 + i * 16 + quad * 4);
                *(floatx4*)p = acc[i][j];
            }
    }
    __syncthreads();
    if (kp == 0) {
        float* pslice = part + (size_t)bz * M * N;
        #pragma unroll
        for (int j = 0; j < 2; ++j) {
            const int col = bn * BN + wn + j * 16 + l16;
            #pragma unroll
            for (int i = 0; i < 2; ++i) {
                const floatx4 po = *(const floatx4*)(
                    scrb + ((wsp * 32 + j * 16 + l16) * 36 + i * 16 + quad * 4));
                const int row0 = bm * BM + wm + i * 16 + quad * 4;
                #pragma unroll
                for (int r = 0; r < 4; ++r)
                    pslice[(size_t)(row0 + r) * N + col] = acc[i][j][r] + po[r];
            }
        }
    }
}

// ---------------- phase 3: sum partials + bias -> out ----------------
__global__ __launch_bounds__(256)
void reduce_bias(const float* __restrict__ part, const float* __restrict__ bias,
                 float* __restrict__ out)
{
    const size_t off = 4 * ((size_t)blockIdx.x * 256 + threadIdx.x);
    constexpr size_t MN = (size_t)M * N;
    float4_t s = *(const float4_t*)(part + off);
    s += *(const float4_t*)(part + MN + off);
    s += *(const float4_t*)(part + 2 * MN + off);
    s += *(const float4_t*)(part + 3 * MN + off);
    s += *(const float4_t*)(bias + (off & (N - 1)));
    *(float4_t*)(out + off) = s;
}

extern "C" void kernel_launch(void* const* d_in, const int* in_sizes, int n_in,
                              void* d_out, int out_size, void* d_ws, size_t ws_size,
                              hipStream_t stream) {
    const float* x    = (const float*)d_in[0];   // (512, 2048)
    const float* w    = (const float*)d_in[1];   // (2048, 2048) = (N, K)
    const float* bias = (const float*)d_in[2];   // (2048,)
    float* out = (float*)d_out;                  // (512, 2048)

    unsigned long long* xb = (unsigned long long*)d_ws;          // 2 MB bf16 x
    unsigned long long* wb = xb + NX / 4;                        // 8 MB bf16 W
    float* part = (float*)((char*)d_ws + (size_t)(NX + NW) * 2); // 16 MB partials

    convert_bf16<<<NCONV4 / 256, 256, 0, stream>>>(x, w, xb, wb);

    dim3 grid(N / BN, M / BM, KSPLIT);           // (32, 8, 4) = 1024 blocks
    memristor_gemm<<<grid, 512, 0, stream>>>(
        (const __hip_bfloat16*)xb, (const __hip_bfloat16*)wb, part);

    reduce_bias<<<(M * N / 4) / 256, 256, 0, stream>>>(part, bias, out);
}